// Round 6
// baseline (358.093 us; speedup 1.0000x reference)
//
#include <hip/hip_runtime.h>
#include <stdint.h>
#include <stddef.h>

// AttentiveTransformer: B=65536, D_IN=128, F=512, fp32
#define NROWS 65536
#define DK 128
#define NF 512
#define LDS_H 528               // halves per LDS row: 528*2B=1056B, 16B-aligned rows
#define BN_EPS 1e-3f

typedef __attribute__((ext_vector_type(8))) short short8;     // 8 x bf16
typedef __attribute__((ext_vector_type(8))) _Float16 half8;   // 8 x fp16
typedef __attribute__((ext_vector_type(4))) float f32x4;

__device__ __forceinline__ unsigned short f2bf(float f) {
  unsigned int u = __builtin_bit_cast(unsigned int, f);
  u += 0x7fffu + ((u >> 16) & 1u);     // RNE
  return (unsigned short)(u >> 16);
}
__device__ __forceinline__ float bf2f(unsigned short h) {
  unsigned int u = ((unsigned int)h) << 16;
  return __builtin_bit_cast(float, u);
}

// ---------------------------------------------------------------------------
// Prep: fold BN scale alpha into W, transpose to [512][128], split bf16 hi/lo.
// ---------------------------------------------------------------------------
__global__ void prep_kernel(const float* __restrict__ W,
                            const float* __restrict__ bias,
                            const float* __restrict__ gamma,
                            const float* __restrict__ beta,
                            const float* __restrict__ mean,
                            const float* __restrict__ var,
                            unsigned short* __restrict__ wt_hi,
                            unsigned short* __restrict__ wt_lo,
                            float* __restrict__ delta) {
  int bid = blockIdx.x, tid = threadIdx.x;
  if (bid < 256) {
    int idx = bid * 256 + tid;        // over [512][128]
    int f = idx >> 7, d = idx & 127;
    float a = gamma[f] * rsqrtf(var[f] + BN_EPS);
    float wv = W[(size_t)d * NF + f] * a;   // alpha folded into weights
    unsigned short wh = f2bf(wv);
    wt_hi[idx] = wh;                  // wt[f][d], contiguous stores
    wt_lo[idx] = f2bf(wv - bf2f(wh));
  } else {
#pragma unroll
    for (int i = 0; i < 2; ++i) {
      int f = tid + i * 256;
      float a = gamma[f] * rsqrtf(var[f] + BN_EPS);
      delta[f] = (bias[f] - mean[f]) * a + beta[f];
    }
  }
}

// ---------------------------------------------------------------------------
// Kernel A: GEMM + BN only. 512 threads (8 waves), 32 rows/block.
// Wave w computes cols [64w,64w+64) x 32 rows via split-bf16 MFMA (verified
// R1/R4 layout), +delta, fp16 z -> LDS transpose, then coalesced fp32 z
// stores INTO d_out (kernel B overwrites it in place, row-local => no race).
// No prior stream, no data-dependent loop: pure throughput kernel.
// ---------------------------------------------------------------------------
__global__ __launch_bounds__(512, 4) void gemm_z_kernel(
    const float* __restrict__ inp,            // [65536][128]
    const unsigned short* __restrict__ wt_hi, // [512][128] bf16 hi (alpha-folded)
    const unsigned short* __restrict__ wt_lo, // [512][128] bf16 lo
    const float* __restrict__ delta,          // [512]
    float* __restrict__ zout) {               // [65536][512] (= d_out)
  __shared__ _Float16 zsh[32 * LDS_H];        // 33792 B

  const int tid = threadIdx.x;
  const int w = tid >> 6;        // wave 0..7
  const int l = tid & 63;
  const int q = l >> 4;          // quad 0..3
  const int li = l & 15;
  const int r0 = blockIdx.x * 32;
  const int n0 = w * 64;         // this wave's column slice

  // ---- A fragments: load + split-convert (2 m-tiles, 32 rows) ----
  short8 ah[2][4], al[2][4];
#pragma unroll
  for (int m = 0; m < 2; ++m) {
    const float* arow = inp + (size_t)(r0 + m * 16 + li) * DK + q * 8;
#pragma unroll
    for (int kk = 0; kk < 4; ++kk) {
      float4 v0 = *(const float4*)(arow + kk * 32);
      float4 v1 = *(const float4*)(arow + kk * 32 + 4);
      float av[8] = {v0.x, v0.y, v0.z, v0.w, v1.x, v1.y, v1.z, v1.w};
      short8 h, lo;
#pragma unroll
      for (int j = 0; j < 8; ++j) {
        unsigned short hb = f2bf(av[j]);
        h[j] = (short)hb;
        lo[j] = (short)f2bf(av[j] - bf2f(hb));
      }
      ah[m][kk] = h;
      al[m][kk] = lo;
    }
  }

  float dv[4];
#pragma unroll
  for (int t = 0; t < 4; ++t) dv[t] = delta[n0 + t * 16 + li];

  // ---- MFMA, 3-product split-bf16, 4 col-tiles ----
  f32x4 acc[2][4];
#pragma unroll
  for (int m = 0; m < 2; ++m)
#pragma unroll
    for (int t = 0; t < 4; ++t) acc[m][t] = (f32x4){0.f, 0.f, 0.f, 0.f};

#pragma unroll
  for (int t = 0; t < 4; ++t) {
    const unsigned short* wbh = wt_hi + (size_t)(n0 + t * 16 + li) * DK + q * 8;
    const unsigned short* wbl = wt_lo + (size_t)(n0 + t * 16 + li) * DK + q * 8;
    short8 WH0 = *(const short8*)(wbh);
    short8 WL0 = *(const short8*)(wbl);
    short8 WH1 = *(const short8*)(wbh + 32);
    short8 WL1 = *(const short8*)(wbl + 32);
    short8 WH2 = *(const short8*)(wbh + 64);
    short8 WL2 = *(const short8*)(wbl + 64);
    short8 WH3 = *(const short8*)(wbh + 96);
    short8 WL3 = *(const short8*)(wbl + 96);
    short8 WH[4] = {WH0, WH1, WH2, WH3};
    short8 WL[4] = {WL0, WL1, WL2, WL3};
#pragma unroll
    for (int kk = 0; kk < 4; ++kk) {
#pragma unroll
      for (int m = 0; m < 2; ++m) {
        acc[m][t] = __builtin_amdgcn_mfma_f32_16x16x32_bf16(ah[m][kk], WH[kk], acc[m][t], 0, 0, 0);
        acc[m][t] = __builtin_amdgcn_mfma_f32_16x16x32_bf16(al[m][kk], WH[kk], acc[m][t], 0, 0, 0);
        acc[m][t] = __builtin_amdgcn_mfma_f32_16x16x32_bf16(ah[m][kk], WL[kk], acc[m][t], 0, 0, 0);
      }
    }
  }

  // ---- +delta, fp16 convert, LDS transpose ----
#pragma unroll
  for (int t = 0; t < 4; ++t) {
    int col = n0 + t * 16 + li;
#pragma unroll
    for (int m = 0; m < 2; ++m) {
#pragma unroll
      for (int r = 0; r < 4; ++r) {
        zsh[(m * 16 + q * 4 + r) * LDS_H + col] = (_Float16)(acc[m][t][r] + dv[t]);
      }
    }
  }
  __syncthreads();

  // ---- coalesced fp32 z stores: 16-lane group = one row ----
  const int g = tid >> 4;        // 0..31
  const int li2 = tid & 15;
  float* orow = zout + (size_t)(r0 + g) * NF + li2 * 8;
#pragma unroll
  for (int j = 0; j < 4; ++j) {
    half8 hv = *(const half8*)&zsh[g * LDS_H + li2 * 8 + 128 * j];
    f32x4 o0, o1;
#pragma unroll
    for (int r = 0; r < 4; ++r) {
      o0[r] = (float)hv[r];
      o1[r] = (float)hv[4 + r];
    }
    *(f32x4*)(orow + 128 * j) = o0;
    *(f32x4*)(orow + 128 * j + 4) = o1;
  }
}

// ---------------------------------------------------------------------------
// Kernel B: streaming prior-scaled sparsemax, in place on d_out.
// One wave per row (8 elems/lane), 4 waves/block, NO barrier/LDS: loads
// pipeline freely, ~30 VGPR -> high occupancy. Michelot fixed-point with
// full-wave xor reductions; all lanes agree after reduction so the
// convergence branch is wave-uniform.
// ---------------------------------------------------------------------------
__global__ __launch_bounds__(256, 8) void sparsemax_kernel(
    const float* __restrict__ prior,   // [65536][512]
    float* __restrict__ io) {          // [65536][512]: z in, mask out
  const int l = threadIdx.x & 63;
  const int wv = threadIdx.x >> 6;
  const size_t row = (size_t)blockIdx.x * 4 + wv;
  float* base = io + row * NF + l * 8;
  const float* pbase = prior + row * NF + l * 8;

  f32x4 z0 = *(const f32x4*)(base);
  f32x4 z1 = *(const f32x4*)(base + 4);
  f32x4 p0 = *(const f32x4*)(pbase);
  f32x4 p1 = *(const f32x4*)(pbase + 4);

  float z[8];
#pragma unroll
  for (int r = 0; r < 4; ++r) {
    z[r] = z0[r] * p0[r];
    z[4 + r] = z1[r] * p1[r];
  }

  float mx = z[0];
#pragma unroll
  for (int j = 1; j < 8; ++j) mx = fmaxf(mx, z[j]);
#pragma unroll
  for (int off = 1; off <= 32; off <<= 1) mx = fmaxf(mx, __shfl_xor(mx, off, 64));

  // Michelot fixed-point: tau <- (sum_S - 1)/|S|, S = {z > tau}
  float tau = mx - 1.0f;
  float cprev = -1.0f;
  for (int it = 0; it < 40; ++it) {
    float s = 0.0f, c = 0.0f;
#pragma unroll
    for (int j = 0; j < 8; ++j) {
      bool in = z[j] > tau;
      s += in ? z[j] : 0.0f;
      c += in ? 1.0f : 0.0f;
    }
#pragma unroll
    for (int off = 1; off <= 32; off <<= 1) {
      s += __shfl_xor(s, off, 64);
      c += __shfl_xor(c, off, 64);
    }
    tau = (s - 1.0f) / c;
    if (c == cprev) break;      // uniform across the wave after full reduction
    cprev = c;
  }

  f32x4 o0, o1;
#pragma unroll
  for (int r = 0; r < 4; ++r) {
    o0[r] = fmaxf(z[r] - tau, 0.0f);
    o1[r] = fmaxf(z[4 + r] - tau, 0.0f);
  }
  *(f32x4*)(base) = o0;
  *(f32x4*)(base + 4) = o1;
}

// ---------------------------------------------------------------------------
extern "C" void kernel_launch(void* const* d_in, const int* in_sizes, int n_in,
                              void* d_out, int out_size, void* d_ws, size_t ws_size,
                              hipStream_t stream) {
  const float* inp   = (const float*)d_in[0];   // [65536][128]
  const float* prior = (const float*)d_in[1];   // [65536][512]
  const float* W     = (const float*)d_in[2];   // [128][512]
  const float* bias  = (const float*)d_in[3];   // [512]
  const float* gamma = (const float*)d_in[4];
  const float* beta  = (const float*)d_in[5];
  const float* mean  = (const float*)d_in[6];
  const float* var   = (const float*)d_in[7];
  float* out = (float*)d_out;

  // workspace carve: 131072 + 131072 + 2048 bytes
  unsigned short* wt_hi = (unsigned short*)d_ws;
  unsigned short* wt_lo = wt_hi + (size_t)NF * DK;
  float* delta = (float*)(wt_lo + (size_t)NF * DK);

  prep_kernel<<<257, 256, 0, stream>>>(W, bias, gamma, beta, mean, var,
                                       wt_hi, wt_lo, delta);
  gemm_z_kernel<<<NROWS / 32, 512, 0, stream>>>(inp, wt_hi, wt_lo, delta, out);
  sparsemax_kernel<<<NROWS / 4, 256, 0, stream>>>(prior, out);
}